// Round 3
// baseline (200.777 us; speedup 1.0000x reference)
//
#include <hip/hip_runtime.h>

#define NB 32
#define NC 3
#define NK 64
#define KS 7
#define IH 224
#define IW 224
#define OH 218
#define OW 218
#define OHW (OH * OW)
#define RG 4          // output rows per group (rows-inner)
#define GROUPS 2      // groups per block -> 8 rows/block
#define NSTG 23       // ceil(RG*21*70 / 256)

typedef float  f32x4 __attribute__((ext_vector_type(4)));
typedef short  s16x8 __attribute__((ext_vector_type(8)));

static __device__ __forceinline__ unsigned short f2bf(float f) {
  unsigned int u = __float_as_uint(f);
  u += 0x7FFFu + ((u >> 16) & 1u);
  return (unsigned short)(u >> 16);
}

// XOR block-swizzle on a 32-u16 (64 B) row: 16B-block ^= (row>>1)&3.
static __device__ __forceinline__ int swz(int r, int ci) {
  return (((ci >> 3) ^ ((r >> 1) & 3)) << 3) | (ci & 7);
}

// ---------------- prep kernels ----------------

// fused: x -> bf16, s = sum_c x^2 (LDS), row box -> t[b][h][ow]
__global__ void k_prep_xrow(const float* __restrict__ x, unsigned short* __restrict__ xb,
                            float* __restrict__ t) {
  __shared__ float s_lds[IW];
  const int n  = blockIdx.x;          // NB*IH
  const int b  = n / IH;
  const int h  = n - b * IH;
  const int px = threadIdx.x;
  if (px < IW) {
    float acc = 0.f;
#pragma unroll
    for (int c = 0; c < NC; ++c) {
      size_t idx = ((size_t)(b * NC + c) * IH + h) * IW + px;
      float v = x[idx];
      xb[idx] = f2bf(v);
      acc += v * v;
    }
    s_lds[px] = acc;
  }
  __syncthreads();
  if (px < OW) {
    float acc = 0.f;
#pragma unroll
    for (int j = 0; j < KS; ++j) acc += s_lds[px + j];
    t[(size_t)(b * IH + h) * OW + px] = acc;
  }
}

// col box: x2[b][oh][ow] = sum_{i<7} t[b][oh+i][ow]
__global__ void k_colbox(const float* __restrict__ t, float* __restrict__ x2) {
  int n = blockIdx.x * 256 + threadIdx.x;            // NB*OH*OW
  if (n >= NB * OH * OW) return;
  int b = n / (OH * OW);
  int r = n - b * (OH * OW);
  int oh = r / OW;
  int ow = r - oh * OW;
  const float* col = t + (size_t)(b * IH + oh) * OW + ow;
  float acc = 0.f;
#pragma unroll
  for (int i = 0; i < KS; ++i) acc += col[i * OW];
  x2[n] = acc;
}

// WTg[row=j*64+k][ci'(swizzled, 32)] = bf16(memes[k][c][i][j]); zeros at ci>=21.
__global__ void k_prep_w(const float* __restrict__ memes, unsigned short* __restrict__ WTg,
                         float* __restrict__ m2inv) {
  int k = threadIdx.x;
  if (k >= NK) return;
  const float* mk = memes + k * (NC * KS * KS);
  float m2 = 0.f;
  for (int c = 0; c < NC; ++c)
    for (int i = 0; i < KS; ++i)
      for (int j = 0; j < KS; ++j) {
        float v = mk[(c * KS + i) * KS + j];
        m2 += v * v;
        int row = j * NK + k;
        WTg[row * 32 + swz(row, c * KS + i)] = f2bf(v);
      }
  for (int j = 0; j < KS; ++j) {
    int row = j * NK + k;
    for (int ci = NC * KS; ci < 32; ++ci)
      WTg[row * 32 + swz(row, ci)] = 0;
  }
  m2inv[k] = 1.0f / m2;
}

// ---------------- staging (issue-early / write-late) ----------------
// One group = RG rows x 21 ci x 70 t = 5880 elems over 256 threads * NSTG.
static __device__ __forceinline__ void xt_issue(unsigned short v[NSTG],
    const unsigned short* __restrict__ xb, int b, int oh0, int ow0, int tid) {
#pragma unroll
  for (int m = 0; m < NSTG; ++m) {
    int idx = tid + 256 * m;
    unsigned short val = 0;
    if (idx < RG * 21 * 70) {
      int r   = idx / 1470;
      int rem = idx - 1470 * r;
      int ci  = rem / 70;
      int t   = rem - 70 * ci;
      int c   = ci / 7;
      int i   = ci - 7 * c;
      int oh  = oh0 + r;
      int ow  = ow0 + t;
      if (oh < OH && ow < IW)
        val = xb[((size_t)(b * NC + c) * IH + (oh + i)) * IW + ow];
    }
    v[m] = val;
  }
}

static __device__ __forceinline__ void xt_write(unsigned short* __restrict__ XT,
    const unsigned short v[NSTG], int tid) {
#pragma unroll
  for (int m = 0; m < NSTG; ++m) {
    int idx = tid + 256 * m;
    if (idx < RG * 21 * 70) {
      int r   = idx / 1470;
      int rem = idx - 1470 * r;
      int ci  = rem / 70;
      int t   = rem - 70 * ci;
      XT[r * 2304 + t * 32 + swz(t, ci)] = v[m];
    }
  }
}

// ---------------- main MFMA kernel ----------------
// Block: 256 threads (4 waves), 3 blocks/CU. Per group: RG rows x 64 ow x 64 k.
// j-outer rows-inner: A fragments loaded once per j for all RG rows.
__global__ __launch_bounds__(256, 3) void k_main(
    const unsigned short* __restrict__ xb, const float* __restrict__ x2g,
    const unsigned short* __restrict__ WTg, const float* __restrict__ m2inv,
    float* __restrict__ out) {
  __shared__ __align__(16) unsigned short WTl[KS * NK * 32];   // 28672 B
  __shared__ __align__(16) unsigned short XTl[RG * 72 * 32];   // 18432 B
  __shared__ float m2l[NK];

  const int tid  = threadIdx.x;
  const int w    = tid >> 6;
  const int lane = tid & 63;
  const int lg   = lane >> 4;
  const int lr   = lane & 15;

  const int ow0 = blockIdx.x * 64;
  const int ohb = blockIdx.y * (RG * GROUPS);
  const int b   = blockIdx.z;

  // WT: linear async copy global->LDS (28 x 1024 B)
  for (int ch = w; ch < 28; ch += 4) {
    const unsigned short* g = WTg + ch * 512 + lane * 8;
    unsigned short* l = WTl + ch * 512;
    __builtin_amdgcn_global_load_lds((const __attribute__((address_space(1))) void*)g,
                                     (__attribute__((address_space(3))) void*)l, 16, 0, 0);
  }
  if (tid < NK) m2l[tid] = m2inv[tid];

  // zero ci pads 21..31 (written once; xt_write never touches them)
  for (int idx = tid; idx < RG * 72 * 11; idx += 256) {
    int tt = idx / 11;
    int cz = 21 + (idx - 11 * tt);
    int r  = tt / 72;
    int t  = tt - 72 * r;
    XTl[r * 2304 + t * 32 + swz(t, cz)] = 0;
  }

  unsigned short s0[NSTG];
  xt_issue(s0, xb, b, ohb, ow0, tid);
  xt_write(XTl, s0, tid);
  asm volatile("s_waitcnt vmcnt(0) lgkmcnt(0)" ::: "memory");  // WT lds + XT writes
  __builtin_amdgcn_s_barrier();

  const int px  = w * 16 + lr;
  const int swa = (lr >> 1) & 3;

#pragma unroll
  for (int g = 0; g < GROUPS; ++g) {
    const int oh0 = ohb + g * RG;

    unsigned short s1[NSTG];
    if (g + 1 < GROUPS) xt_issue(s1, xb, b, oh0 + RG, ow0, tid);  // loads fly over MFMAs

    if (oh0 < OH) {                       // block-uniform
      f32x4 acc[RG][4];
#pragma unroll
      for (int r = 0; r < RG; ++r)
#pragma unroll
        for (int q = 0; q < 4; ++q) acc[r][q] = (f32x4){0.f, 0.f, 0.f, 0.f};

#pragma unroll
      for (int j = 0; j < KS; ++j) {
        const unsigned short* ab = WTl + j * (NK * 32) + lr * 32 + ((lg ^ swa) << 3);
        s16x8 a0 = *(const s16x8*)&ab[0];
        s16x8 a1 = *(const s16x8*)&ab[512];
        s16x8 a2 = *(const s16x8*)&ab[1024];
        s16x8 a3 = *(const s16x8*)&ab[1536];
        const int t = px + j;
        const int boff = t * 32 + ((lg ^ ((t >> 1) & 3)) << 3);
#pragma unroll
        for (int r = 0; r < RG; ++r) {
          s16x8 bf_ = *(const s16x8*)&XTl[r * 2304 + boff];
          acc[r][0] = __builtin_amdgcn_mfma_f32_16x16x32_bf16(a0, bf_, acc[r][0], 0, 0, 0);
          acc[r][1] = __builtin_amdgcn_mfma_f32_16x16x32_bf16(a1, bf_, acc[r][1], 0, 0, 0);
          acc[r][2] = __builtin_amdgcn_mfma_f32_16x16x32_bf16(a2, bf_, acc[r][2], 0, 0, 0);
          acc[r][3] = __builtin_amdgcn_mfma_f32_16x16x32_bf16(a3, bf_, acc[r][3], 0, 0, 0);
        }
      }

      const int ow = ow0 + px;
      if (ow < OW) {
#pragma unroll
        for (int r = 0; r < RG; ++r) {
          const int oh = oh0 + r;
          if (oh < OH) {
            const float x2v = x2g[(size_t)(b * OH + oh) * OW + ow];
            float* ob = out + ((size_t)(b * NK) * OH + oh) * OW + ow;
#pragma unroll
            for (int rr = 0; rr < 4; ++rr) {
              const int k0 = 4 * lg + rr;
              ob[(size_t)(k0)      * OHW] = (x2v - 2.0f * acc[r][0][rr]) * m2l[k0]      + 1.0f;
              ob[(size_t)(k0 + 16) * OHW] = (x2v - 2.0f * acc[r][1][rr]) * m2l[k0 + 16] + 1.0f;
              ob[(size_t)(k0 + 32) * OHW] = (x2v - 2.0f * acc[r][2][rr]) * m2l[k0 + 32] + 1.0f;
              ob[(size_t)(k0 + 48) * OHW] = (x2v - 2.0f * acc[r][3][rr]) * m2l[k0 + 48] + 1.0f;
            }
          }
        }
      }
    }

    if (g + 1 < GROUPS) {
      // readers done with XTl before overwrite; writers complete before readers resume.
      // lgkm-only waits: output stores stay in flight across the boundary.
      asm volatile("s_waitcnt lgkmcnt(0)" ::: "memory");
      __builtin_amdgcn_s_barrier();
      xt_write(XTl, s1, tid);
      asm volatile("s_waitcnt lgkmcnt(0)" ::: "memory");
      __builtin_amdgcn_s_barrier();
    }
  }
}

// ---------------- launch ----------------
extern "C" void kernel_launch(void* const* d_in, const int* in_sizes, int n_in,
                              void* d_out, int out_size, void* d_ws, size_t ws_size,
                              hipStream_t stream) {
  const float* x     = (const float*)d_in[0];   // [32,3,224,224]
  const float* memes = (const float*)d_in[1];   // [64,3,7,7]
  float* out = (float*)d_out;                   // [32,64,218,218]

  char* ws = (char*)d_ws;
  unsigned short* xb  = (unsigned short*)(ws);                 // 9,633,792 B
  float* t            = (float*)(ws + 9633792);                // 6,250,496 B
  float* x2           = (float*)(ws + 15884288);               // 6,083,072 B
  unsigned short* WTg = (unsigned short*)(ws + 21967360);      // 28,672 B
  float* m2inv        = (float*)(ws + 21996032);               // 256 B

  (void)in_sizes; (void)n_in; (void)out_size; (void)ws_size;

  k_prep_xrow<<<NB * IH, 256, 0, stream>>>(x, xb, t);
  k_colbox<<<(NB * OH * OW + 255) / 256, 256, 0, stream>>>(t, x2);
  k_prep_w<<<1, 64, 0, stream>>>(memes, WTg, m2inv);

  dim3 grid((OW + 63) / 64, (OH + RG * GROUPS - 1) / (RG * GROUPS), NB);
  k_main<<<grid, 256, 0, stream>>>(xb, x2, WTg, m2inv, out);
}